// Round 3
// baseline (9475.194 us; speedup 1.0000x reference)
//
#include <hip/hip_runtime.h>
#include <hip/hip_bf16.h>
#include <cstdint>

#define N_TOT 65536
#define NG 64
#define GS 1024
#define IN_DIM 34
#define WIDTH 126
#define EMB 128
#define PROP 32
#define SPACE 4
#define KNN 8
#define NCONV 5
#define FEAT (IN_DIM + NCONV*EMB)   /* 674 */
#define CATW (EMB + 2*PROP)         /* 192 */
#define AGGW (2*PROP)               /* 64 */
#define TS 16

// ---------------------------------------------------------------------------
// Generic tiled GEMM, all f32, split A operand:
//   A row = [A1 (K1 cols, stride lda1) | A2 (K2 cols, stride lda2)]
//   accum==0: C = act(A@W + bias) (+ addx slice)
//   accum==1: C += A@W           (no bias/act/addx)
// act: 0 = identity, 1 = ELU (alpha=1). bias may be null.
// ---------------------------------------------------------------------------
__global__ void gemm_kernel(const float* __restrict__ A1, int lda1, int K1,
                            const float* __restrict__ A2, int lda2, int K2,
                            const float* __restrict__ W,
                            const float* __restrict__ bias,
                            float* __restrict__ C, int ldc, int accum,
                            const float* __restrict__ addx, int addx_ld, int addx_off,
                            int M, int Nn, int act)
{
  __shared__ float As[TS][TS+1];
  __shared__ float Bs[TS][TS+1];
  const int K = K1 + K2;
  int tx = threadIdx.x, ty = threadIdx.y;
  int row = blockIdx.x*TS + ty;
  int col = blockIdx.y*TS + tx;
  float acc = 0.f;
  for (int k0 = 0; k0 < K; k0 += TS){
    int ka = k0 + tx;
    float av = 0.f;
    if (row < M && ka < K){
      av = (ka < K1) ? A1[(size_t)row*lda1 + ka]
                     : A2[(size_t)row*lda2 + (ka - K1)];
    }
    As[ty][tx] = av;
    int kb = k0 + ty;
    Bs[ty][tx] = (kb < K && col < Nn) ? W[(size_t)kb*Nn + col] : 0.f;
    __syncthreads();
    #pragma unroll
    for (int kk = 0; kk < TS; ++kk) acc += As[ty][kk]*Bs[kk][tx];
    __syncthreads();
  }
  if (row < M && col < Nn){
    if (accum){
      C[(size_t)row*ldc + col] += acc;
    } else {
      if (bias) acc += bias[col];
      if (act == 1) acc = (acc > 0.f) ? acc : expm1f(acc);
      if (addx) acc += addx[(size_t)row*addx_ld + addx_off + col];
      C[(size_t)row*ldc + col] = acc;
    }
  }
}

// ---------------------------------------------------------------------------
// In-place v = elu(v + bias[col]) over N x W126
// ---------------------------------------------------------------------------
__global__ void bias_elu_kernel(float* __restrict__ v, const float* __restrict__ bias){
  int idx = blockIdx.x*blockDim.x + threadIdx.x;
  if (idx < N_TOT*WIDTH){
    int col = idx % WIDTH;
    float a = v[idx] + bias[col];
    v[idx] = (a > 0.f) ? a : expm1f(a);
  }
}

// ---------------------------------------------------------------------------
// Per-graph kNN (K=8, incl. self) + weighted mean/max aggregation.
// One block (1024 threads) per graph. agg[row] = [mean(32) | max(32)].
// Selection: expansion-form d2 (matches reference); weights: diff form.
// ---------------------------------------------------------------------------
__global__ __launch_bounds__(GS)
void knn_agg_kernel(const float* __restrict__ h,
                    const float* __restrict__ sp,
                    float* __restrict__ agg)
{
  __shared__ float ss[GS][SPACE];
  __shared__ float sn2[GS];
  int g = blockIdx.x;
  int i = threadIdx.x;

  const float4 sv = ((const float4*)(sp + (size_t)g*GS*SPACE))[i];
  ss[i][0] = sv.x; ss[i][1] = sv.y; ss[i][2] = sv.z; ss[i][3] = sv.w;
  float myn2 = sv.x*sv.x + sv.y*sv.y + sv.z*sv.z + sv.w*sv.w;
  sn2[i] = myn2;
  __syncthreads();

  float si0 = sv.x, si1 = sv.y, si2 = sv.z, si3 = sv.w;

  float bd[KNN]; int bi[KNN];
  #pragma unroll
  for (int k = 0; k < KNN; ++k){ bd[k] = 1e30f; bi[k] = 0; }

  for (int j = 0; j < GS; ++j){
    float dot = si0*ss[j][0] + si1*ss[j][1] + si2*ss[j][2] + si3*ss[j][3];
    float d2 = myn2 + sn2[j] - 2.f*dot;
    if (d2 < bd[KNN-1]){
      #pragma unroll
      for (int q = KNN-1; q >= 1; --q){
        bool cq = d2 < bd[q];
        bool cp = d2 < bd[q-1];
        float nv = cp ? bd[q-1] : d2;
        int   ni = cp ? bi[q-1] : j;
        if (cq){ bd[q] = nv; bi[q] = ni; }
      }
      if (d2 < bd[0]){ bd[0] = d2; bi[0] = j; }
    }
  }

  float w[KNN];
  #pragma unroll
  for (int k = 0; k < KNN; ++k){
    int j = bi[k];
    float d0 = si0 - ss[j][0], d1 = si1 - ss[j][1];
    float d2_ = si2 - ss[j][2], d3 = si3 - ss[j][3];
    float dd = d0*d0 + d1*d1 + d2_*d2_ + d3*d3;
    w[k] = expf(-10.f*dd);
  }

  float msum[PROP], mmax[PROP];
  #pragma unroll
  for (int p = 0; p < PROP; ++p){ msum[p] = 0.f; mmax[p] = -1e30f; }
  const float* hg = h + (size_t)g*GS*PROP;
  #pragma unroll
  for (int k = 0; k < KNN; ++k){
    const float* hr = hg + (size_t)bi[k]*PROP;
    float wk = w[k];
    #pragma unroll
    for (int p = 0; p < PROP; ++p){
      float v = hr[p]*wk;
      msum[p] += v;
      mmax[p] = fmaxf(mmax[p], v);
    }
  }

  size_t row = (size_t)g*GS + i;
  float* arow = agg + row*AGGW;
  #pragma unroll
  for (int p = 0; p < PROP; ++p){
    arow[p]        = msum[p]*(1.f/KNN);
    arow[PROP + p] = mmax[p];
  }
}

// ---------------------------------------------------------------------------
extern "C" void kernel_launch(void* const* d_in, const int* in_sizes, int n_in,
                              void* d_out, int out_size, void* d_ws, size_t ws_size,
                              hipStream_t stream)
{
  const float* x     = (const float*)d_in[0];
  // d_in[1] = batch (int32) — implied by fixed layout, unused
  const float* n0W1  = (const float*)d_in[2];
  const float* n0b1  = (const float*)d_in[3];
  const float* n0W23 = (const float*)d_in[4];
  const float* n0b23 = (const float*)d_in[5];
  const float* n0W4  = (const float*)d_in[6];
  const float* n0b4  = (const float*)d_in[7];
  const float* cWh   = (const float*)d_in[8];
  const float* cbh   = (const float*)d_in[9];
  const float* cWs   = (const float*)d_in[10];
  const float* cbs   = (const float*)d_in[11];
  const float* cWo   = (const float*)d_in[12];
  const float* cbo   = (const float*)d_in[13];
  const float* HW1   = (const float*)d_in[14];
  const float* Hb1   = (const float*)d_in[15];
  const float* HW23  = (const float*)d_in[16];
  const float* Hb23  = (const float*)d_in[17];
  const float* Wid   = (const float*)d_in[18];
  const float* bid   = (const float*)d_in[19];
  const float* Wreg  = (const float*)d_in[20];
  const float* breg  = (const float*)d_in[21];
  const float* Wch   = (const float*)d_in[22];
  const float* bch   = (const float*)d_in[23];
  float* out = (float*)d_out;
  (void)in_sizes; (void)n_in; (void)out_size; (void)ws_size;

  // ---- workspace layout (~158.5 MiB) ----
  char* wsp = (char*)d_ws;
  float* P     = (float*)(wsp);                          // N x 128 f32
  float* Q     = (float*)(wsp + 33554432);               // N x 128 f32
  float* haccA = (float*)(wsp + 67108864);               // N x 126 f32
  float* haccB = (float*)(wsp + 100139008);              // N x 126 f32
  char*  R     = wsp + 133169152;                        // 33.0 MB shared region
  float* hbuf  = (float*)(R);                            // N x 32 f32 (conv-time)
  float* sbuf  = (float*)(R + 8388608);                  // N x 4  f32
  float* aggb  = (float*)(R + 9437184);                  // N x 64 f32
  float* t2    = (float*)(R);                            // N x 126 f32 (head-time)

  auto gemm = [&](const float* A1, int lda1, int K1,
                  const float* A2, int lda2, int K2,
                  const float* W, const float* b,
                  float* C, int ldc, int accum,
                  const float* addx, int addx_ld, int addx_off,
                  int Nn, int act){
    dim3 grid((N_TOT+TS-1)/TS, (Nn+TS-1)/TS);
    dim3 blk(TS, TS);
    hipLaunchKernelGGL(gemm_kernel, grid, blk, 0, stream,
        A1, lda1, K1, A2, lda2, K2, W, b, C, ldc, accum,
        addx, addx_ld, addx_off, N_TOT, Nn, act);
  };

  auto run_embedding = [&](){
    // 34 ->126 ->126 ->126 ->128 (ELU on first three), result -> P
    // scratch: haccA (t1), t2 (R)
    gemm(x, IN_DIM, IN_DIM, nullptr,0,0, n0W1, n0b1,
         haccA, WIDTH, 0, nullptr,0,0, WIDTH, 1);
    gemm(haccA, WIDTH, WIDTH, nullptr,0,0, n0W23, n0b23,
         t2, WIDTH, 0, nullptr,0,0, WIDTH, 1);
    gemm(t2, WIDTH, WIDTH, nullptr,0,0, n0W23 + WIDTH*WIDTH, n0b23 + WIDTH,
         haccA, WIDTH, 0, nullptr,0,0, WIDTH, 1);
    gemm(haccA, WIDTH, WIDTH, nullptr,0,0, n0W4, n0b4,
         P, EMB, 0, nullptr,0,0, EMB, 0);
  };

  // finish a head given its accumulated layer-1 pre-activation in hacc
  auto finish_head = [&](int hidx, float* hacc, float* dst, int dst_ld, int out_dim,
                         const float* Wl, const float* bl,
                         const float* addx, int addx_ld, int addx_off){
    // hacc = elu(hacc + b1)
    {
      int tot = N_TOT*WIDTH;
      hipLaunchKernelGGL(bias_elu_kernel, dim3((tot+255)/256), dim3(256), 0, stream,
                         hacc, Hb1 + hidx*WIDTH);
    }
    gemm(hacc, WIDTH, WIDTH, nullptr,0,0,
         HW23 + (size_t)(hidx*2+0)*WIDTH*WIDTH, Hb23 + (hidx*2+0)*WIDTH,
         t2, WIDTH, 0, nullptr,0,0, WIDTH, 1);
    gemm(t2, WIDTH, WIDTH, nullptr,0,0,
         HW23 + (size_t)(hidx*2+1)*WIDTH*WIDTH, Hb23 + (hidx*2+1)*WIDTH,
         hacc, WIDTH, 0, nullptr,0,0, WIDTH, 1);
    gemm(hacc, WIDTH, WIDTH, nullptr,0,0, Wl, bl,
         dst, dst_ld, 0, addx, addx_ld, addx_off, out_dim, 0);
  };

  for (int s = 0; s < 2; ++s){
    run_embedding();                       // -> P (uses haccA, t2 as scratch)

    // init head layer-1 accumulators with the x-part of W1 (rows 0..33)
    int h0 = (s == 0) ? 0 : 1;
    gemm(x, IN_DIM, IN_DIM, nullptr,0,0,
         HW1 + (size_t)h0*FEAT*WIDTH, nullptr,
         haccA, WIDTH, 0, nullptr,0,0, WIDTH, 0);
    if (s == 1){
      gemm(x, IN_DIM, IN_DIM, nullptr,0,0,
           HW1 + (size_t)2*FEAT*WIDTH, nullptr,
           haccB, WIDTH, 0, nullptr,0,0, WIDTH, 0);
    }

    float* cur = P; float* nxt = Q;
    for (int cv = 0; cv < NCONV; ++cv){
      int pidx = s*NCONV + cv;
      // h = cur @ Wh + bh (128->32)
      gemm(cur, EMB, EMB, nullptr,0,0,
           cWh + (size_t)pidx*EMB*PROP, cbh + pidx*PROP,
           hbuf, PROP, 0, nullptr,0,0, PROP, 0);
      // s = cur @ Ws + bs (128->4)
      gemm(cur, EMB, EMB, nullptr,0,0,
           cWs + (size_t)pidx*EMB*SPACE, cbs + pidx*SPACE,
           sbuf, SPACE, 0, nullptr,0,0, SPACE, 0);
      // kNN + aggregate -> aggb (N x 64)
      hipLaunchKernelGGL(knn_agg_kernel, dim3(NG), dim3(GS), 0, stream,
                         hbuf, sbuf, aggb);
      // o_cv = [cur | agg] @ Wo + bo (192->128) -> nxt
      gemm(cur, EMB, EMB, aggb, AGGW, AGGW,
           cWo + (size_t)pidx*CATW*EMB, cbo + pidx*EMB,
           nxt, EMB, 0, nullptr,0,0, EMB, 0);
      // head accumulation: hacc += o_cv @ W1[rows 34+cv*128 .. +128]
      gemm(nxt, EMB, EMB, nullptr,0,0,
           HW1 + (size_t)h0*FEAT*WIDTH + (size_t)(IN_DIM + cv*EMB)*WIDTH, nullptr,
           haccA, WIDTH, 1, nullptr,0,0, WIDTH, 0);
      if (s == 1){
        gemm(nxt, EMB, EMB, nullptr,0,0,
             HW1 + (size_t)2*FEAT*WIDTH + (size_t)(IN_DIM + cv*EMB)*WIDTH, nullptr,
             haccB, WIDTH, 1, nullptr,0,0, WIDTH, 0);
      }
      float* tmp = cur; cur = nxt; nxt = tmp;
    }

    if (s == 0){
      finish_head(0, haccA, out, 8, 8, Wid, bid, nullptr, 0, 0);
    } else {
      finish_head(1, haccA, out + (size_t)N_TOT*8, 4, 4, Wreg, breg, x, IN_DIM, 1);
      finish_head(2, haccB, out + (size_t)N_TOT*12, 1, 1, Wch, bch, nullptr, 0, 0);
    }
  }
}

// Round 4
// 8278.021 us; speedup vs baseline: 1.1446x; 1.1446x over previous
//
#include <hip/hip_runtime.h>
#include <hip/hip_bf16.h>
#include <cstdint>

#define N_TOT 65536
#define NG 64
#define GS 1024
#define IN_DIM 34
#define WIDTH 126
#define EMB 128
#define PROP 32
#define SPACE 4
#define KNN 8
#define NCONV 5
#define FEAT (IN_DIM + NCONV*EMB)   /* 674 */
#define CATW (EMB + 2*PROP)         /* 192 */
#define AGGW (2*PROP)               /* 64 */

// ---------------------------------------------------------------------------
// Register-tiled f32 GEMM. 256 threads. Split A operand [A1 | A2].
//   accum==0: C = act(A@W + bias) (+ addx slice)
//   accum==1: C += A@W
// A staged transposed in LDS (conflict-free); each thread computes TMxTN.
// M fixed = N_TOT (divisible by BM).
// ---------------------------------------------------------------------------
template<int BM, int BN, int BK, int TM, int TN>
__global__ __launch_bounds__(256)
void gemm_tile_kernel(const float* __restrict__ A1, int lda1, int K1,
                      const float* __restrict__ A2, int lda2, int K2,
                      const float* __restrict__ W, const float* __restrict__ bias,
                      float* __restrict__ C, int ldc, int accum,
                      const float* __restrict__ addx, int addx_ld, int addx_off,
                      int Nn, int act)
{
  constexpr int LDA = BM + 1;
  constexpr int LDB = BN + 4;
  __shared__ float As[BK * LDA];   // As[k][m]
  __shared__ float Bs[BK * LDB];   // Bs[k][n]
  const int K = K1 + K2;
  const int t = threadIdx.x;
  const int bm0 = blockIdx.x * BM;
  const int bn0 = blockIdx.y * BN;
  const int tx = t % (BN / TN);
  const int ty = t / (BN / TN);
  const int m0 = ty * TM;
  const int n0 = tx * TN;

  float acc[TM][TN];
  #pragma unroll
  for (int i = 0; i < TM; ++i)
    #pragma unroll
    for (int j = 0; j < TN; ++j) acc[i][j] = 0.f;

  for (int k0 = 0; k0 < K; k0 += BK){
    #pragma unroll
    for (int i = 0; i < (BM*BK)/256; ++i){
      int idx = t + i*256;
      int r  = idx / BK;
      int kk = idx % BK;
      int ka = k0 + kk;
      float v = 0.f;
      size_t rr = (size_t)(bm0 + r);
      if (ka < K)
        v = (ka < K1) ? A1[rr*lda1 + ka] : A2[rr*lda2 + (ka - K1)];
      As[kk*LDA + r] = v;
    }
    #pragma unroll
    for (int i = 0; i < (BN*BK)/256; ++i){
      int idx = t + i*256;
      int kk = idx / BN;
      int n  = idx % BN;
      int kb = k0 + kk;
      int col = bn0 + n;
      Bs[kk*LDB + n] = (kb < K && col < Nn) ? W[(size_t)kb*Nn + col] : 0.f;
    }
    __syncthreads();
    #pragma unroll
    for (int kk = 0; kk < BK; ++kk){
      float a[TM], b[TN];
      #pragma unroll
      for (int i = 0; i < TM; ++i) a[i] = As[kk*LDA + m0 + i];
      #pragma unroll
      for (int j = 0; j < TN; ++j) b[j] = Bs[kk*LDB + n0 + j];
      #pragma unroll
      for (int i = 0; i < TM; ++i)
        #pragma unroll
        for (int j = 0; j < TN; ++j)
          acc[i][j] += a[i]*b[j];
    }
    __syncthreads();
  }

  #pragma unroll
  for (int i = 0; i < TM; ++i){
    size_t row = (size_t)(bm0 + m0 + i);
    #pragma unroll
    for (int j = 0; j < TN; ++j){
      int col = bn0 + n0 + j;
      if (col < Nn){
        float v = acc[i][j];
        if (accum){
          C[row*ldc + col] += v;
        } else {
          if (bias) v += bias[col];
          if (act == 1) v = (v > 0.f) ? v : expm1f(v);
          if (addx) v += addx[row*addx_ld + addx_off + col];
          C[row*ldc + col] = v;
        }
      }
    }
  }
}

// ---------------------------------------------------------------------------
// In-place v = elu(v + bias[col]) over N x WIDTH
// ---------------------------------------------------------------------------
__global__ void bias_elu_kernel(float* __restrict__ v, const float* __restrict__ bias){
  int idx = blockIdx.x*blockDim.x + threadIdx.x;
  if (idx < N_TOT*WIDTH){
    int col = idx % WIDTH;
    float a = v[idx] + bias[col];
    v[idx] = (a > 0.f) ? a : expm1f(a);
  }
}

// ---------------------------------------------------------------------------
// Per-graph kNN (K=8, incl. self) + weighted mean/max aggregation.
// 8 blocks per graph x 128 threads; graph's s + |s|^2 staged in LDS.
// agg[row] = [mean(32) | max(32)].
// ---------------------------------------------------------------------------
#define KNN_BPG 8
#define KNN_THR 128

__global__ __launch_bounds__(KNN_THR)
void knn_agg_kernel(const float* __restrict__ h,
                    const float* __restrict__ sp,
                    float* __restrict__ agg)
{
  __shared__ float4 ssv[GS];
  __shared__ float sn2[GS];
  int g     = blockIdx.x / KNN_BPG;
  int chunk = blockIdx.x % KNN_BPG;
  int t = threadIdx.x;

  const float4* spg = (const float4*)(sp + (size_t)g*GS*SPACE);
  for (int i = t; i < GS; i += KNN_THR){
    float4 v = spg[i];
    ssv[i] = v;
    sn2[i] = v.x*v.x + v.y*v.y + v.z*v.z + v.w*v.w;
  }
  __syncthreads();

  int i = chunk*KNN_THR + t;            // row within graph
  float4 sv = ssv[i];
  float myn2 = sn2[i];
  float si0 = sv.x, si1 = sv.y, si2 = sv.z, si3 = sv.w;

  float bd[KNN]; int bi[KNN];
  #pragma unroll
  for (int k = 0; k < KNN; ++k){ bd[k] = 1e30f; bi[k] = 0; }

  for (int j = 0; j < GS; ++j){
    float4 sj = ssv[j];
    float dot = si0*sj.x + si1*sj.y + si2*sj.z + si3*sj.w;
    float d2 = myn2 + sn2[j] - 2.f*dot;
    if (d2 < bd[KNN-1]){
      #pragma unroll
      for (int q = KNN-1; q >= 1; --q){
        bool cq = d2 < bd[q];
        bool cp = d2 < bd[q-1];
        float nv = cp ? bd[q-1] : d2;
        int   ni = cp ? bi[q-1] : j;
        if (cq){ bd[q] = nv; bi[q] = ni; }
      }
      if (d2 < bd[0]){ bd[0] = d2; bi[0] = j; }
    }
  }

  float w[KNN];
  #pragma unroll
  for (int k = 0; k < KNN; ++k){
    float4 sj = ssv[bi[k]];
    float d0 = si0 - sj.x, d1 = si1 - sj.y, d2_ = si2 - sj.z, d3 = si3 - sj.w;
    float dd = d0*d0 + d1*d1 + d2_*d2_ + d3*d3;
    w[k] = expf(-10.f*dd);
  }

  float msum[PROP], mmax[PROP];
  #pragma unroll
  for (int p = 0; p < PROP; ++p){ msum[p] = 0.f; mmax[p] = -1e30f; }
  const float* hg = h + (size_t)g*GS*PROP;
  #pragma unroll
  for (int k = 0; k < KNN; ++k){
    const float4* hr = (const float4*)(hg + (size_t)bi[k]*PROP);
    float wk = w[k];
    #pragma unroll
    for (int p4 = 0; p4 < PROP/4; ++p4){
      float4 hv = hr[p4];
      float v0 = hv.x*wk, v1 = hv.y*wk, v2 = hv.z*wk, v3 = hv.w*wk;
      msum[p4*4+0] += v0; mmax[p4*4+0] = fmaxf(mmax[p4*4+0], v0);
      msum[p4*4+1] += v1; mmax[p4*4+1] = fmaxf(mmax[p4*4+1], v1);
      msum[p4*4+2] += v2; mmax[p4*4+2] = fmaxf(mmax[p4*4+2], v2);
      msum[p4*4+3] += v3; mmax[p4*4+3] = fmaxf(mmax[p4*4+3], v3);
    }
  }

  size_t row = (size_t)g*GS + i;
  float* arow = agg + row*AGGW;
  #pragma unroll
  for (int p = 0; p < PROP; ++p){
    arow[p]        = msum[p]*(1.f/KNN);
    arow[PROP + p] = mmax[p];
  }
}

// ---------------------------------------------------------------------------
extern "C" void kernel_launch(void* const* d_in, const int* in_sizes, int n_in,
                              void* d_out, int out_size, void* d_ws, size_t ws_size,
                              hipStream_t stream)
{
  const float* x     = (const float*)d_in[0];
  const float* n0W1  = (const float*)d_in[2];
  const float* n0b1  = (const float*)d_in[3];
  const float* n0W23 = (const float*)d_in[4];
  const float* n0b23 = (const float*)d_in[5];
  const float* n0W4  = (const float*)d_in[6];
  const float* n0b4  = (const float*)d_in[7];
  const float* cWh   = (const float*)d_in[8];
  const float* cbh   = (const float*)d_in[9];
  const float* cWs   = (const float*)d_in[10];
  const float* cbs   = (const float*)d_in[11];
  const float* cWo   = (const float*)d_in[12];
  const float* cbo   = (const float*)d_in[13];
  const float* HW1   = (const float*)d_in[14];
  const float* Hb1   = (const float*)d_in[15];
  const float* HW23  = (const float*)d_in[16];
  const float* Hb23  = (const float*)d_in[17];
  const float* Wid   = (const float*)d_in[18];
  const float* bid   = (const float*)d_in[19];
  const float* Wreg  = (const float*)d_in[20];
  const float* breg  = (const float*)d_in[21];
  const float* Wch   = (const float*)d_in[22];
  const float* bch   = (const float*)d_in[23];
  float* out = (float*)d_out;
  (void)in_sizes; (void)n_in; (void)out_size; (void)ws_size;

  // ---- workspace layout (~158.5 MiB) ----
  char* wsp = (char*)d_ws;
  float* P     = (float*)(wsp);                          // N x 128
  float* Q     = (float*)(wsp + 33554432);               // N x 128
  float* haccA = (float*)(wsp + 67108864);               // N x 126
  float* haccB = (float*)(wsp + 100139008);              // N x 126
  char*  R     = wsp + 133169152;                        // shared region
  float* hbuf  = (float*)(R);                            // N x 32 (conv-time)
  float* sbuf  = (float*)(R + 8388608);                  // N x 4
  float* aggb  = (float*)(R + 9437184);                  // N x 64
  float* t2    = (float*)(R);                            // N x 126 (head-time)

  // big: 128x128x32 tile, 8x8 per thread
  auto gemmL = [&](const float* A1, int lda1, int K1,
                   const float* A2, int lda2, int K2,
                   const float* W, const float* b,
                   float* C, int ldc, int accum,
                   const float* addx, int addx_ld, int addx_off,
                   int Nn, int act){
    dim3 grid(N_TOT/128, (Nn+127)/128);
    hipLaunchKernelGGL((gemm_tile_kernel<128,128,32,8,8>), grid, dim3(256), 0, stream,
        A1, lda1, K1, A2, lda2, K2, W, b, C, ldc, accum,
        addx, addx_ld, addx_off, Nn, act);
  };
  // small: 64x64x32 tile, 4x4 per thread (narrow Nn)
  auto gemmS = [&](const float* A1, int lda1, int K1,
                   const float* W, const float* b,
                   float* C, int ldc,
                   const float* addx, int addx_ld, int addx_off,
                   int Nn, int act){
    dim3 grid(N_TOT/64, (Nn+63)/64);
    hipLaunchKernelGGL((gemm_tile_kernel<64,64,32,4,4>), grid, dim3(256), 0, stream,
        A1, lda1, K1, (const float*)nullptr, 0, 0, W, b, C, ldc, 0,
        addx, addx_ld, addx_off, Nn, act);
  };

  auto run_embedding = [&](){
    // 34 ->126 ->126 ->126 ->128 (ELU on first three) -> P; scratch haccA,t2
    gemmL(x, IN_DIM, IN_DIM, nullptr,0,0, n0W1, n0b1,
          haccA, WIDTH, 0, nullptr,0,0, WIDTH, 1);
    gemmL(haccA, WIDTH, WIDTH, nullptr,0,0, n0W23, n0b23,
          t2, WIDTH, 0, nullptr,0,0, WIDTH, 1);
    gemmL(t2, WIDTH, WIDTH, nullptr,0,0, n0W23 + WIDTH*WIDTH, n0b23 + WIDTH,
          haccA, WIDTH, 0, nullptr,0,0, WIDTH, 1);
    gemmL(haccA, WIDTH, WIDTH, nullptr,0,0, n0W4, n0b4,
          P, EMB, 0, nullptr,0,0, EMB, 0);
  };

  auto finish_head = [&](int hidx, float* hacc, float* dst, int dst_ld, int out_dim,
                         const float* Wl, const float* bl,
                         const float* addx, int addx_ld, int addx_off){
    {
      int tot = N_TOT*WIDTH;
      hipLaunchKernelGGL(bias_elu_kernel, dim3((tot+255)/256), dim3(256), 0, stream,
                         hacc, Hb1 + hidx*WIDTH);
    }
    gemmL(hacc, WIDTH, WIDTH, nullptr,0,0,
          HW23 + (size_t)(hidx*2+0)*WIDTH*WIDTH, Hb23 + (hidx*2+0)*WIDTH,
          t2, WIDTH, 0, nullptr,0,0, WIDTH, 1);
    gemmL(t2, WIDTH, WIDTH, nullptr,0,0,
          HW23 + (size_t)(hidx*2+1)*WIDTH*WIDTH, Hb23 + (hidx*2+1)*WIDTH,
          hacc, WIDTH, 0, nullptr,0,0, WIDTH, 1);
    gemmS(hacc, WIDTH, WIDTH, Wl, bl,
          dst, dst_ld, addx, addx_ld, addx_off, out_dim, 0);
  };

  for (int s = 0; s < 2; ++s){
    run_embedding();                       // -> P

    int h0 = (s == 0) ? 0 : 1;
    gemmL(x, IN_DIM, IN_DIM, nullptr,0,0,
          HW1 + (size_t)h0*FEAT*WIDTH, nullptr,
          haccA, WIDTH, 0, nullptr,0,0, WIDTH, 0);
    if (s == 1){
      gemmL(x, IN_DIM, IN_DIM, nullptr,0,0,
            HW1 + (size_t)2*FEAT*WIDTH, nullptr,
            haccB, WIDTH, 0, nullptr,0,0, WIDTH, 0);
    }

    float* cur = P; float* nxt = Q;
    for (int cv = 0; cv < NCONV; ++cv){
      int pidx = s*NCONV + cv;
      // h = cur @ Wh + bh (128->32)
      gemmS(cur, EMB, EMB,
            cWh + (size_t)pidx*EMB*PROP, cbh + pidx*PROP,
            hbuf, PROP, nullptr,0,0, PROP, 0);
      // s = cur @ Ws + bs (128->4)
      gemmS(cur, EMB, EMB,
            cWs + (size_t)pidx*EMB*SPACE, cbs + pidx*SPACE,
            sbuf, SPACE, nullptr,0,0, SPACE, 0);
      // kNN + aggregate -> aggb (N x 64)
      hipLaunchKernelGGL(knn_agg_kernel, dim3(NG*KNN_BPG), dim3(KNN_THR), 0, stream,
                         hbuf, sbuf, aggb);
      // o_cv = [cur | agg] @ Wo + bo (192->128) -> nxt
      gemmL(cur, EMB, EMB, aggb, AGGW, AGGW,
            cWo + (size_t)pidx*CATW*EMB, cbo + pidx*EMB,
            nxt, EMB, 0, nullptr,0,0, EMB, 0);
      // hacc += o_cv @ W1[rows 34+cv*128 .. +128]
      gemmL(nxt, EMB, EMB, nullptr,0,0,
            HW1 + (size_t)h0*FEAT*WIDTH + (size_t)(IN_DIM + cv*EMB)*WIDTH, nullptr,
            haccA, WIDTH, 1, nullptr,0,0, WIDTH, 0);
      if (s == 1){
        gemmL(nxt, EMB, EMB, nullptr,0,0,
              HW1 + (size_t)2*FEAT*WIDTH + (size_t)(IN_DIM + cv*EMB)*WIDTH, nullptr,
              haccB, WIDTH, 1, nullptr,0,0, WIDTH, 0);
      }
      float* tmp = cur; cur = nxt; nxt = tmp;
    }

    if (s == 0){
      finish_head(0, haccA, out, 8, 8, Wid, bid, nullptr, 0, 0);
    } else {
      finish_head(1, haccA, out + (size_t)N_TOT*8, 4, 4, Wreg, breg, x, IN_DIM, 1);
      finish_head(2, haccB, out + (size_t)N_TOT*12, 1, 1, Wch, bch, nullptr, 0, 0);
    }
  }
}

// Round 5
// 8104.314 us; speedup vs baseline: 1.1692x; 1.0214x over previous
//
#include <hip/hip_runtime.h>
#include <hip/hip_bf16.h>
#include <cstdint>

#define N_TOT 65536
#define NG 64
#define GS 1024
#define IN_DIM 34
#define WIDTH 126
#define EMB 128
#define PROP 32
#define SPACE 4
#define KNN 8
#define NCONV 5
#define FEAT (IN_DIM + NCONV*EMB)   /* 674 */
#define CATW (EMB + 2*PROP)         /* 192 */
#define AGGW (2*PROP)               /* 64 */
#define PRJW 36                     /* h(32) | s(4) */

// ---------------------------------------------------------------------------
// Register-tiled f32 GEMM. 256 threads. Split A operand [A1 | A2].
//   accum==0: C = act(A@W + bias) (+ addx slice)
//   accum==1: C += A@W
//   accum==2: C = elu(C + A@W + bias)
// Optional dual output (W2/C2/bias2): grid.y doubled, upper half computes the
// same A against a second weight matrix (used for the two reg-stack heads).
// LDS rows padded to +4 floats -> 16B-aligned float4 fragment reads.
// ---------------------------------------------------------------------------
template<int BM, int BN, int BK, int TM, int TN>
__global__ __launch_bounds__(256)
void gemm_tile_kernel(const float* __restrict__ A1, int lda1, int K1,
                      const float* __restrict__ A2, int lda2, int K2,
                      const float* __restrict__ W, const float* __restrict__ bias,
                      float* __restrict__ C, int ldc, int accum,
                      const float* __restrict__ W2, float* __restrict__ C2,
                      const float* __restrict__ bias2,
                      const float* __restrict__ addx, int addx_ld, int addx_off,
                      int Nn, int act)
{
  constexpr int LDA = BM + 4;
  constexpr int LDB = BN + 4;
  __shared__ float As[BK * LDA];   // As[k][m]
  __shared__ float Bs[BK * LDB];   // Bs[k][n]
  const int K = K1 + K2;
  const int t = threadIdx.x;
  const int bm0 = blockIdx.x * BM;

  // dual-output resolution
  const int ny = (Nn + BN - 1) / BN;
  int by = blockIdx.y;
  const float* Wp = W;  float* Cp = C;  const float* bp = bias;
  if (W2 != nullptr && by >= ny){ Wp = W2; Cp = C2; bp = bias2; by -= ny; }
  const int bn0 = by * BN;

  const int tx = t % (BN / TN);
  const int ty = t / (BN / TN);
  const int m0 = ty * TM;
  const int n0 = tx * TN;

  float acc[TM][TN];
  #pragma unroll
  for (int i = 0; i < TM; ++i)
    #pragma unroll
    for (int j = 0; j < TN; ++j) acc[i][j] = 0.f;

  for (int k0 = 0; k0 < K; k0 += BK){
    #pragma unroll
    for (int i = 0; i < (BM*BK)/256; ++i){
      int idx = t + i*256;
      int r  = idx / BK;
      int kk = idx % BK;
      int ka = k0 + kk;
      float v = 0.f;
      size_t rr = (size_t)(bm0 + r);
      if (ka < K)
        v = (ka < K1) ? A1[rr*lda1 + ka] : A2[rr*lda2 + (ka - K1)];
      As[kk*LDA + r] = v;
    }
    #pragma unroll
    for (int i = 0; i < (BN*BK)/256; ++i){
      int idx = t + i*256;
      int kk = idx / BN;
      int n  = idx % BN;
      int kb = k0 + kk;
      int col = bn0 + n;
      Bs[kk*LDB + n] = (kb < K && col < Nn) ? Wp[(size_t)kb*Nn + col] : 0.f;
    }
    __syncthreads();
    #pragma unroll
    for (int kk = 0; kk < BK; ++kk){
      float a[TM], b[TN];
      #pragma unroll
      for (int i4 = 0; i4 < TM/4; ++i4){
        float4 v = *(const float4*)(&As[kk*LDA + m0 + i4*4]);
        a[i4*4+0] = v.x; a[i4*4+1] = v.y; a[i4*4+2] = v.z; a[i4*4+3] = v.w;
      }
      #pragma unroll
      for (int j4 = 0; j4 < TN/4; ++j4){
        float4 v = *(const float4*)(&Bs[kk*LDB + n0 + j4*4]);
        b[j4*4+0] = v.x; b[j4*4+1] = v.y; b[j4*4+2] = v.z; b[j4*4+3] = v.w;
      }
      #pragma unroll
      for (int i = 0; i < TM; ++i)
        #pragma unroll
        for (int j = 0; j < TN; ++j)
          acc[i][j] += a[i]*b[j];
    }
    __syncthreads();
  }

  #pragma unroll
  for (int i = 0; i < TM; ++i){
    size_t row = (size_t)(bm0 + m0 + i);
    #pragma unroll
    for (int j = 0; j < TN; ++j){
      int col = bn0 + n0 + j;
      if (col < Nn){
        float v = acc[i][j];
        if (accum == 1){
          Cp[row*ldc + col] += v;
        } else if (accum == 2){
          v += Cp[row*ldc + col] + bp[col];
          Cp[row*ldc + col] = (v > 0.f) ? v : expm1f(v);
        } else {
          if (bp) v += bp[col];
          if (act == 1) v = (v > 0.f) ? v : expm1f(v);
          if (addx) v += addx[row*addx_ld + addx_off + col];
          Cp[row*ldc + col] = v;
        }
      }
    }
  }
}

// ---------------------------------------------------------------------------
// Per-graph kNN (K=8, incl. self) + weighted mean/max aggregation.
// proj: N x 36 rows = [h(32) | s(4)]. 16 blocks/graph x 64 threads.
// j-scan unrolled x8 with min-skip test; insert cascade order-preserving.
// agg[row] = [mean(32) | max(32)].
// ---------------------------------------------------------------------------
#define KNN_THR 64
#define KNN_BPG 16

__global__ __launch_bounds__(KNN_THR)
void knn_agg_kernel(const float* __restrict__ proj, float* __restrict__ agg)
{
  __shared__ float4 ssv[GS];
  __shared__ float sn2[GS];
  int g     = blockIdx.x / KNN_BPG;
  int chunk = blockIdx.x % KNN_BPG;
  int t = threadIdx.x;

  const float* pg = proj + (size_t)g*GS*PRJW;
  for (int i = t; i < GS; i += KNN_THR){
    float4 v = *(const float4*)(pg + (size_t)i*PRJW + PROP);
    ssv[i] = v;
    sn2[i] = v.x*v.x + v.y*v.y + v.z*v.z + v.w*v.w;
  }
  __syncthreads();

  int i = chunk*KNN_THR + t;            // row within graph
  float4 sv = ssv[i];
  float myn2 = sn2[i];
  float si0 = sv.x, si1 = sv.y, si2 = sv.z, si3 = sv.w;

  float bd[KNN]; int bi[KNN];
  #pragma unroll
  for (int k = 0; k < KNN; ++k){ bd[k] = 1e30f; bi[k] = 0; }

  for (int j0 = 0; j0 < GS; j0 += 8){
    float dv[8];
    #pragma unroll
    for (int u = 0; u < 8; ++u){
      float4 sj = ssv[j0+u];
      float dot = si0*sj.x + si1*sj.y + si2*sj.z + si3*sj.w;
      dv[u] = myn2 + sn2[j0+u] - 2.f*dot;
    }
    float mn = fminf(fminf(fminf(dv[0],dv[1]), fminf(dv[2],dv[3])),
                     fminf(fminf(dv[4],dv[5]), fminf(dv[6],dv[7])));
    if (mn < bd[KNN-1]){
      #pragma unroll
      for (int u = 0; u < 8; ++u){
        float d2 = dv[u];
        if (d2 < bd[KNN-1]){
          int j = j0 + u;
          #pragma unroll
          for (int q = KNN-1; q >= 1; --q){
            bool cq = d2 < bd[q];
            bool cp = d2 < bd[q-1];
            float nv = cp ? bd[q-1] : d2;
            int   ni = cp ? bi[q-1] : j;
            if (cq){ bd[q] = nv; bi[q] = ni; }
          }
          if (d2 < bd[0]){ bd[0] = d2; bi[0] = j; }
        }
      }
    }
  }

  float w[KNN];
  #pragma unroll
  for (int k = 0; k < KNN; ++k){
    float4 sj = ssv[bi[k]];
    float d0 = si0 - sj.x, d1 = si1 - sj.y, d2_ = si2 - sj.z, d3 = si3 - sj.w;
    float dd = d0*d0 + d1*d1 + d2_*d2_ + d3*d3;
    w[k] = expf(-10.f*dd);
  }

  float msum[PROP], mmax[PROP];
  #pragma unroll
  for (int p = 0; p < PROP; ++p){ msum[p] = 0.f; mmax[p] = -1e30f; }
  #pragma unroll
  for (int k = 0; k < KNN; ++k){
    const float* hr = pg + (size_t)bi[k]*PRJW;
    float wk = w[k];
    #pragma unroll
    for (int p4 = 0; p4 < PROP/4; ++p4){
      float4 hv = *(const float4*)(hr + p4*4);
      float v0 = hv.x*wk, v1 = hv.y*wk, v2 = hv.z*wk, v3 = hv.w*wk;
      msum[p4*4+0] += v0; mmax[p4*4+0] = fmaxf(mmax[p4*4+0], v0);
      msum[p4*4+1] += v1; mmax[p4*4+1] = fmaxf(mmax[p4*4+1], v1);
      msum[p4*4+2] += v2; mmax[p4*4+2] = fmaxf(mmax[p4*4+2], v2);
      msum[p4*4+3] += v3; mmax[p4*4+3] = fmaxf(mmax[p4*4+3], v3);
    }
  }

  size_t row = (size_t)g*GS + i;
  float* arow = agg + row*AGGW;
  #pragma unroll
  for (int p = 0; p < PROP; ++p){
    arow[p]        = msum[p]*(1.f/KNN);
    arow[PROP + p] = mmax[p];
  }
}

// ---------------------------------------------------------------------------
extern "C" void kernel_launch(void* const* d_in, const int* in_sizes, int n_in,
                              void* d_out, int out_size, void* d_ws, size_t ws_size,
                              hipStream_t stream)
{
  const float* x     = (const float*)d_in[0];
  const float* n0W1  = (const float*)d_in[2];
  const float* n0b1  = (const float*)d_in[3];
  const float* n0W23 = (const float*)d_in[4];
  const float* n0b23 = (const float*)d_in[5];
  const float* n0W4  = (const float*)d_in[6];
  const float* n0b4  = (const float*)d_in[7];
  const float* cWh   = (const float*)d_in[8];
  const float* cbh   = (const float*)d_in[9];
  const float* cWs   = (const float*)d_in[10];
  const float* cbs   = (const float*)d_in[11];
  const float* cWo   = (const float*)d_in[12];
  const float* cbo   = (const float*)d_in[13];
  const float* HW1   = (const float*)d_in[14];
  const float* Hb1   = (const float*)d_in[15];
  const float* HW23  = (const float*)d_in[16];
  const float* Hb23  = (const float*)d_in[17];
  const float* Wid   = (const float*)d_in[18];
  const float* bid   = (const float*)d_in[19];
  const float* Wreg  = (const float*)d_in[20];
  const float* breg  = (const float*)d_in[21];
  const float* Wch   = (const float*)d_in[22];
  const float* bch   = (const float*)d_in[23];
  float* out = (float*)d_out;
  (void)in_sizes; (void)n_in; (void)out_size; (void)ws_size;

  // ---- workspace layout (~158.5 MiB) ----
  char* wsp = (char*)d_ws;
  float* P     = (float*)(wsp);                          // N x 128
  float* Q     = (float*)(wsp + 33554432);               // N x 128
  float* haccA = (float*)(wsp + 67108864);               // N x 126
  float* haccB = (float*)(wsp + 100139008);              // N x 126
  char*  R     = wsp + 133169152;                        // shared region
  float* projb = (float*)(R);                            // N x 36 (conv-time)
  float* aggb  = (float*)(R + 9568256);                  // N x 64
  float* t2    = (float*)(R);                            // N x 126 (head/emb-time)

  auto gemmL = [&](const float* A1, int lda1, int K1,
                   const float* A2, int lda2, int K2,
                   const float* W, const float* b,
                   float* C, int ldc, int accum,
                   const float* W2, float* C2, const float* b2,
                   const float* addx, int addx_ld, int addx_off,
                   int Nn, int act){
    int ny = (Nn + 127)/128;
    dim3 grid(N_TOT/128, W2 ? ny*2 : ny);
    hipLaunchKernelGGL((gemm_tile_kernel<128,128,32,8,8>), grid, dim3(256), 0, stream,
        A1, lda1, K1, A2, lda2, K2, W, b, C, ldc, accum,
        W2, C2, b2, addx, addx_ld, addx_off, Nn, act);
  };
  auto gemmS = [&](const float* A1, int lda1, int K1,
                   const float* W, const float* b,
                   float* C, int ldc,
                   const float* addx, int addx_ld, int addx_off,
                   int Nn, int act){
    dim3 grid(N_TOT/64, (Nn+63)/64);
    hipLaunchKernelGGL((gemm_tile_kernel<64,64,32,4,4>), grid, dim3(256), 0, stream,
        A1, lda1, K1, (const float*)nullptr, 0, 0, W, b, C, ldc, 0,
        (const float*)nullptr, (float*)nullptr, (const float*)nullptr,
        addx, addx_ld, addx_off, Nn, act);
  };

  auto run_embedding = [&](){
    // 34 ->126 ->126 ->126 ->128 (ELU on first three) -> P; scratch haccA, t2
    gemmL(x, IN_DIM, IN_DIM, nullptr,0,0, n0W1, n0b1,
          haccA, WIDTH, 0, nullptr,nullptr,nullptr, nullptr,0,0, WIDTH, 1);
    gemmL(haccA, WIDTH, WIDTH, nullptr,0,0, n0W23, n0b23,
          t2, WIDTH, 0, nullptr,nullptr,nullptr, nullptr,0,0, WIDTH, 1);
    gemmL(t2, WIDTH, WIDTH, nullptr,0,0, n0W23 + WIDTH*WIDTH, n0b23 + WIDTH,
          haccA, WIDTH, 0, nullptr,nullptr,nullptr, nullptr,0,0, WIDTH, 1);
    gemmL(haccA, WIDTH, WIDTH, nullptr,0,0, n0W4, n0b4,
          P, EMB, 0, nullptr,nullptr,nullptr, nullptr,0,0, EMB, 0);
  };

  // finish a head: hacc already holds elu(f @ W1 + b1)
  auto finish_head = [&](int hidx, float* hacc, float* dst, int dst_ld, int out_dim,
                         const float* Wl, const float* bl,
                         const float* addx, int addx_ld, int addx_off){
    gemmL(hacc, WIDTH, WIDTH, nullptr,0,0,
          HW23 + (size_t)(hidx*2+0)*WIDTH*WIDTH, Hb23 + (hidx*2+0)*WIDTH,
          t2, WIDTH, 0, nullptr,nullptr,nullptr, nullptr,0,0, WIDTH, 1);
    gemmL(t2, WIDTH, WIDTH, nullptr,0,0,
          HW23 + (size_t)(hidx*2+1)*WIDTH*WIDTH, Hb23 + (hidx*2+1)*WIDTH,
          hacc, WIDTH, 0, nullptr,nullptr,nullptr, nullptr,0,0, WIDTH, 1);
    gemmS(hacc, WIDTH, WIDTH, Wl, bl,
          dst, dst_ld, addx, addx_ld, addx_off, out_dim, 0);
  };

  // packed projection weights live nowhere: we run h and s as separate column
  // ranges of one GEMM by passing Wh (Nn=32) and Ws (Nn=4) — instead, do two
  // staged writes into projb: cols 0..31 (h) and 32..35 (s).
  for (int s = 0; s < 2; ++s){
    run_embedding();                       // -> P

    int h0 = (s == 0) ? 0 : 1;
    // head layer-1 init: hacc = x @ W1[rows 0..33]  (dual for stack 2)
    gemmL(x, IN_DIM, IN_DIM, nullptr,0,0,
          HW1 + (size_t)h0*FEAT*WIDTH, nullptr,
          haccA, WIDTH, 0,
          (s==1) ? HW1 + (size_t)2*FEAT*WIDTH : nullptr,
          (s==1) ? haccB : nullptr, nullptr,
          nullptr,0,0, WIDTH, 0);

    float* cur = P; float* nxt = Q;
    for (int cv = 0; cv < NCONV; ++cv){
      int pidx = s*NCONV + cv;
      // projections into projb: h -> cols 0..31, s -> cols 32..35
      gemmS(cur, EMB, EMB,
            cWh + (size_t)pidx*EMB*PROP, cbh + pidx*PROP,
            projb, PRJW, nullptr,0,0, PROP, 0);
      gemmS(cur, EMB, EMB,
            cWs + (size_t)pidx*EMB*SPACE, cbs + pidx*SPACE,
            projb + PROP, PRJW, nullptr,0,0, SPACE, 0);
      // kNN + aggregate -> aggb (N x 64)
      hipLaunchKernelGGL(knn_agg_kernel, dim3(NG*KNN_BPG), dim3(KNN_THR), 0, stream,
                         projb, aggb);
      // o_cv = [cur | agg] @ Wo + bo (192->128) -> nxt
      gemmL(cur, EMB, EMB, aggb, AGGW, AGGW,
            cWo + (size_t)pidx*CATW*EMB, cbo + pidx*EMB,
            nxt, EMB, 0, nullptr,nullptr,nullptr, nullptr,0,0, EMB, 0);
      // hacc += o_cv @ W1[rows 34+cv*128 .. +128]; last conv fuses bias+ELU
      int acc_mode = (cv == NCONV-1) ? 2 : 1;
      gemmL(nxt, EMB, EMB, nullptr,0,0,
            HW1 + (size_t)h0*FEAT*WIDTH + (size_t)(IN_DIM + cv*EMB)*WIDTH,
            (acc_mode==2) ? Hb1 + h0*WIDTH : nullptr,
            haccA, WIDTH, acc_mode,
            (s==1) ? HW1 + (size_t)2*FEAT*WIDTH + (size_t)(IN_DIM + cv*EMB)*WIDTH : nullptr,
            (s==1) ? haccB : nullptr,
            (s==1 && acc_mode==2) ? Hb1 + 2*WIDTH : nullptr,
            nullptr,0,0, WIDTH, 0);
      float* tmp = cur; cur = nxt; nxt = tmp;
    }

    if (s == 0){
      finish_head(0, haccA, out, 8, 8, Wid, bid, nullptr, 0, 0);
    } else {
      finish_head(1, haccA, out + (size_t)N_TOT*8, 4, 4, Wreg, breg, x, IN_DIM, 1);
      finish_head(2, haccB, out + (size_t)N_TOT*12, 1, 1, Wch, bch, nullptr, 0, 0);
    }
  }
}